// Round 6
// baseline (236.547 us; speedup 1.0000x reference)
//
#include <hip/hip_runtime.h>
#include <hip/hip_bf16.h>
#include <stdint.h>

// FlatCritic: B=128, L=512, D_DESC=768, D_STD=128, D_ACT=128, D_CTX=1152, H=512
// out = [q (B*L f32), emb (B*L*128 f32)]
//
// v6: bigger row-tiles to cut per-block weight re-streaming (the invariant cost):
// emb 64-row/512thr blocks (wdf traffic /2), mlp 128-row blocks = 2 sequential
// 64-row sub-tiles sharing one h1 (w2f+w1f traffic /2). Staging structure = v4.

typedef __attribute__((ext_vector_type(8))) short short8_t;
typedef __attribute__((ext_vector_type(4))) short short4_t;
typedef __attribute__((ext_vector_type(4))) float f32x4;
typedef __attribute__((ext_vector_type(4))) unsigned int u32x4;

__device__ inline unsigned short f2bf(float f) {
  union { float f; unsigned u; } v; v.f = f;
  unsigned r = v.u + 0x7FFFu + ((v.u >> 16) & 1u);
  return (unsigned short)(r >> 16);
}

// A-frag pack (mb-major): dst[((mb*NKS+ks)*64+l)*8+j] = bf16(src[(k0+ks*32+(l>>4)*8+j)*ldc + mb*16+(l&15)])
__device__ inline void pack_frags(const float* __restrict__ src, int ldc, int k0, int NKS,
                                  unsigned short* __restrict__ dst, int total, int tid, int n) {
  for (int fi = tid; fi < total; fi += n) {
    int j = fi & 7, lane = (fi >> 3) & 63, rest = fi >> 9;
    int ks = rest % NKS, mb = rest / NKS;
    int c = mb * 16 + (lane & 15);
    int k = k0 + ks * 32 + ((lane >> 4) << 3) + j;
    dst[fi] = f2bf(src[(size_t)k * ldc + c]);
  }
}

__global__ __launch_bounds__(256) void prep_pack(
    const float* __restrict__ Wd, const float* __restrict__ Ws,
    const float* __restrict__ W1, const float* __restrict__ W2,
    unsigned short* __restrict__ wdf, unsigned short* __restrict__ wsf,
    unsigned short* __restrict__ w1f, unsigned short* __restrict__ w2f) {
  int tid = blockIdx.x * 256 + threadIdx.x, n = gridDim.x * 256;
  pack_frags(Wd, 128, 0,    24, wdf,  98304,  tid, n);   // desc proj  [8mb][24ks]
  pack_frags(Ws, 128, 0,    4,  wsf,  16384,  tid, n);   // std proj   [8mb][4ks]
  pack_frags(W1, 512, 1152, 4,  w1f,  65536,  tid, n);   // W1[1152:]  [32mb][4ks]
  pack_frags(W2, 512, 0,    16, w2f,  262144, tid, n);   // W2         [32mb][16ks]
}

// ---------------- cc[b][h] = b1[h] + ctx(b).W1[:1152,h]  (fp32 exact) ----------------
__global__ __launch_bounds__(256) void ctx_cc(
    const float* __restrict__ instr, const float* __restrict__ state, const float* __restrict__ hidden,
    const float* __restrict__ W1, const float* __restrict__ b1, float* __restrict__ cc) {
  int bid = blockIdx.x;
  int b = bid >> 2, part = bid & 3;
  __shared__ float ctx[1152];
  __shared__ float red[256];
  int t = threadIdx.x;
  for (int i = t; i < 512; i += 256) { ctx[i] = instr[b * 512 + i]; ctx[512 + i] = state[b * 512 + i]; }
  if (t < 128) ctx[1024 + t] = hidden[b * 128 + t];
  __syncthreads();
  int hcol = part * 128 + (t & 127);
  int half = t >> 7;
  float acc = 0.f;
  const float* wp = W1 + (size_t)half * 576 * 512 + hcol;
  #pragma unroll 8
  for (int d = 0; d < 576; ++d) acc = fmaf(ctx[half * 576 + d], wp[(size_t)d * 512], acc);
  red[t] = acc;
  __syncthreads();
  if (t < 128) cc[b * 512 + hcol] = red[t] + red[t + 128] + b1[hcol];
}

// ---------------- q_inv[b]: MLP tail on emb=0 rows (f32 W2) ----------------
__global__ __launch_bounds__(256) void qinv_kernel(
    const float* __restrict__ cc, const float* __restrict__ W2, const float* __restrict__ b2,
    const float* __restrict__ W3, const float* __restrict__ b3, float* __restrict__ qinv) {
  int b = blockIdx.x, t = threadIdx.x;
  __shared__ float h1s[512];
  __shared__ float red[256];
  for (int i = t; i < 512; i += 256) h1s[i] = fmaxf(cc[b * 512 + i], 0.f);
  __syncthreads();
  float a0 = b2[t], a1 = b2[t + 256];
  #pragma unroll 4
  for (int c = 0; c < 512; ++c) {
    float x = h1s[c];
    a0 = fmaf(x, W2[(size_t)c * 512 + t], a0);
    a1 = fmaf(x, W2[(size_t)c * 512 + t + 256], a1);
  }
  red[t] = fmaxf(a0, 0.f) * W3[t] + fmaxf(a1, 0.f) * W3[t + 256];
  __syncthreads();
  for (int s = 128; s > 0; s >>= 1) { if (t < s) red[t] += red[t + s]; __syncthreads(); }
  if (t == 0) qinv[b] = fmaxf(red[0] + b3[0], 0.f);
}

// ---------------- E: emb producer. 64-row tiles, 512 threads, grid (8,128) ----------------
// embB layout unchanged (32-row tile units): tile = b*16 + l0/32
__global__ __launch_bounds__(512, 4) void emb_kernel(
    const float* __restrict__ adesc, const float* __restrict__ astd,
    const int* __restrict__ type_ids, const int* __restrict__ lengths,
    const float* __restrict__ bdesc, const float* __restrict__ bstd,
    const unsigned short* __restrict__ wdf, const unsigned short* __restrict__ wsf,
    float* __restrict__ embout, unsigned short* __restrict__ embB) {
  int b = blockIdx.y, lt = blockIdx.x;
  int l0 = lt * 64;
  int t = threadIdx.x;
  int len = lengths[b];
  int nv = len - l0; nv = nv < 0 ? 0 : (nv > 64 ? 64 : nv);
  f32x4 zero4 = {0.f, 0.f, 0.f, 0.f};

  if (nv == 0) {  // fully-invalid tile: emb = 0, embB = 0 (q handled by M)
    f32x4* ep = (f32x4*)(embout + (size_t)(b * 512 + l0) * 128);
    #pragma unroll
    for (int i = 0; i < 4; ++i) ep[t + i * 512] = zero4;
    u32x4 z4 = {0u, 0u, 0u, 0u};
    u32x4* bp = (u32x4*)(embB + (size_t)(b * 16 + lt * 2) * 4096);
    bp[t] = z4; bp[t + 512] = z4;
    return;
  }

  __shared__ __align__(16) unsigned short act[2][64 * 136];  // 34.8 KB
  __shared__ int typeL[64];
  int w = t >> 6, l = t & 63, g = l >> 4, ln = l & 15;

  if (t < 64) typeL[t] = type_ids[b * 512 + l0 + t];

  const float* descB = adesc + (size_t)(b * 512 + l0) * 768;
  const float* stdB  = astd  + (size_t)(b * 512 + l0) * 128;

  __syncthreads();  // typeL ready

  // reg-split staging (T14): issue -> [MFMA prev] -> write
  f32x4 stg[4];
  int r0 = t >> 5, c4 = t & 31;  // rows r0+16i, col quad c4

  auto issue = [&](int kc) {
    bool isStd = (kc == 6);
    #pragma unroll
    for (int i = 0; i < 4; ++i) {
      int r = r0 + i * 16;
      bool ok = (r < nv) && ((typeL[r] == 0) != isStd);
      f32x4 v = zero4;
      if (ok) v = isStd ? *(const f32x4*)(stdB + (size_t)r * 128 + c4 * 4)
                        : *(const f32x4*)(descB + (size_t)r * 768 + kc * 128 + c4 * 4);
      stg[i] = v;
    }
  };
  auto writebuf = [&](int kc) {
    unsigned short* buf = act[kc & 1];
    #pragma unroll
    for (int i = 0; i < 4; ++i) {
      short4_t p;
      p[0] = (short)f2bf(stg[i][0]); p[1] = (short)f2bf(stg[i][1]);
      p[2] = (short)f2bf(stg[i][2]); p[3] = (short)f2bf(stg[i][3]);
      *(short4_t*)&buf[(r0 + i * 16) * 136 + c4 * 4] = p;
    }
  };

  issue(0); writebuf(0);

  f32x4 acc[4];  // wave w owns mb = w (k-rows w*16..w*16+15), nb = 0..3
  #pragma unroll
  for (int nb = 0; nb < 4; ++nb) acc[nb] = zero4;

  for (int kc = 0; kc < 7; ++kc) {
    __syncthreads();  // buf[kc&1] writes visible; prev reads of buf[(kc+1)&1] done
    if (kc < 6) issue(kc + 1);
    const unsigned short* buf = act[kc & 1];
    bool isStd = (kc == 6);
    #pragma unroll
    for (int ks = 0; ks < 4; ++ks) {
      const unsigned short* ap = isStd ? (wsf + (((w * 4 + ks) * 64 + l) << 3))
                                       : (wdf + (((w * 24 + kc * 4 + ks) * 64 + l) << 3));
      short8_t a = *(const short8_t*)ap;
      #pragma unroll
      for (int nb = 0; nb < 4; ++nb) {
        short8_t bb = *(const short8_t*)&buf[(nb * 16 + ln) * 136 + ks * 32 + g * 8];
        acc[nb] = __builtin_amdgcn_mfma_f32_16x16x32_bf16(a, bb, acc[nb], 0, 0, 0);
      }
    }
    if (kc < 6) writebuf(kc + 1);
  }
  __syncthreads();  // last MFMAs (read act[0]) done -> reuse act[0] as E[64][136]

  unsigned short* E = act[0];
  {
    int k0 = w * 16 + g * 4;
    f32x4 bd4 = *(const f32x4*)(bdesc + k0);
    f32x4 bs4 = *(const f32x4*)(bstd + k0);
    #pragma unroll
    for (int nb = 0; nb < 4; ++nb) {
      int r = nb * 16 + ln;
      f32x4 e = acc[nb];
      if (r < nv) { f32x4 bias = (typeL[r] == 0) ? bd4 : bs4; e = e + bias; }
      else e = zero4;
      *(f32x4*)(embout + (size_t)(b * 512 + l0 + r) * 128 + k0) = e;
      short4_t p; p[0] = (short)f2bf(e[0]); p[1] = (short)f2bf(e[1]);
      p[2] = (short)f2bf(e[2]); p[3] = (short)f2bf(e[3]);
      *(short4_t*)&E[r * 136 + k0] = p;
    }
  }
  __syncthreads();

  // export B-frag-linear embB (two 32-row half-tiles): waves 0-3 -> half 0, 4-7 -> half 1
  int h = w >> 2, ks = w & 3;
  unsigned short* eb = embB + (size_t)(b * 16 + lt * 2 + h) * 4096;
  #pragma unroll
  for (int nb2 = 0; nb2 < 2; ++nb2) {
    short8_t v = *(const short8_t*)&E[(h * 32 + nb2 * 16 + ln) * 136 + ks * 32 + g * 8];
    *(short8_t*)&eb[((ks * 2 + nb2) * 64 + l) * 8] = v;
  }
}

// ---------------- M: MLP. 128-row blocks = 2x 64-row sub-tiles, 512 thr, grid (4,128) ----------------
__global__ __launch_bounds__(512, 4) void mlp_kernel(
    const int* __restrict__ lengths,
    const float* __restrict__ b2, const float* __restrict__ W3, const float* __restrict__ b3,
    const unsigned short* __restrict__ w1f, const unsigned short* __restrict__ w2f,
    const float* __restrict__ cc, const float* __restrict__ qinv,
    const unsigned short* __restrict__ embB, float* __restrict__ qout) {
  int b = blockIdx.y, lt = blockIdx.x;
  int base = lt * 128;
  int t = threadIdx.x;
  int len = lengths[b];
  int nvb = len - base; nvb = nvb < 0 ? 0 : (nvb > 128 ? 128 : nvb);

  if (nvb == 0) {
    if (t < 128) qout[(size_t)b * 512 + base + t] = qinv[b];
    return;
  }

  __shared__ __align__(16) unsigned short h1[64 * 520];
  __shared__ float qpart[8][64];
  int w = t >> 6, l = t & 63, g = l >> 4, ln = l & 15;

  for (int s = 0; s < 2; ++s) {
    int l0 = base + s * 64;
    int nv = len - l0; nv = nv < 0 ? 0 : (nv > 64 ? 64 : nv);
    if (nv == 0) {  // block-uniform: tail sub-tile fully invalid
      if (t < 64) qout[(size_t)b * 512 + l0 + t] = qinv[b];
      continue;
    }

    // ===== S1: H1T[c1][r] = cc[b][c1] + sum_k W1e[k][c1]*emb[r][k]
    f32x4 acc1[4][4];
    #pragma unroll
    for (int mbi = 0; mbi < 4; ++mbi) {
      f32x4 ccv = *(const f32x4*)(cc + (size_t)b * 512 + (w * 4 + mbi) * 16 + g * 4);
      #pragma unroll
      for (int nb = 0; nb < 4; ++nb) acc1[mbi][nb] = ccv;
    }
    const unsigned short* ebase = embB + (size_t)(b * 16 + lt * 4 + s * 2) * 4096;
    #pragma unroll
    for (int ks = 0; ks < 4; ++ks) {
      short8_t bfr[4];
      #pragma unroll
      for (int nb = 0; nb < 4; ++nb)
        bfr[nb] = *(const short8_t*)&ebase[(nb >> 1) * 4096 + ((ks * 2 + (nb & 1)) * 64 + l) * 8];
      #pragma unroll
      for (int mbi = 0; mbi < 4; ++mbi) {
        short8_t a = *(const short8_t*)(w1f + ((((w * 4 + mbi) * 4 + ks) * 64 + l) << 3));
        #pragma unroll
        for (int nb = 0; nb < 4; ++nb)
          acc1[mbi][nb] = __builtin_amdgcn_mfma_f32_16x16x32_bf16(a, bfr[nb], acc1[mbi][nb], 0, 0, 0);
      }
    }
    // relu + pack H1 bf16 -> LDS
    #pragma unroll
    for (int mbi = 0; mbi < 4; ++mbi) {
      int c0 = (w * 4 + mbi) * 16 + g * 4;
      #pragma unroll
      for (int nb = 0; nb < 4; ++nb) {
        int r = nb * 16 + ln;
        f32x4 v = acc1[mbi][nb];
        short4_t p;
        p[0] = (short)f2bf(fmaxf(v[0], 0.f)); p[1] = (short)f2bf(fmaxf(v[1], 0.f));
        p[2] = (short)f2bf(fmaxf(v[2], 0.f)); p[3] = (short)f2bf(fmaxf(v[3], 0.f));
        *(short4_t*)&h1[r * 520 + c0] = p;
      }
    }
    __syncthreads();

    // ===== S2: H2T[c2][r] = b2[c2] + sum_c1 W2[c1][c2]*H1[r][c1]
    f32x4 acc2[4][4];
    #pragma unroll
    for (int mbi = 0; mbi < 4; ++mbi) {
      f32x4 b2v = *(const f32x4*)(b2 + (w * 4 + mbi) * 16 + g * 4);
      #pragma unroll
      for (int nb = 0; nb < 4; ++nb) acc2[mbi][nb] = b2v;
    }
    #pragma unroll
    for (int ks = 0; ks < 16; ++ks) {
      short8_t bfr[4];
      #pragma unroll
      for (int nb = 0; nb < 4; ++nb)
        bfr[nb] = *(const short8_t*)&h1[(nb * 16 + ln) * 520 + ks * 32 + g * 8];
      #pragma unroll
      for (int mbi = 0; mbi < 4; ++mbi) {
        short8_t a = *(const short8_t*)(w2f + ((((w * 4 + mbi) * 16 + ks) * 64 + l) << 3));
        #pragma unroll
        for (int nb = 0; nb < 4; ++nb)
          acc2[mbi][nb] = __builtin_amdgcn_mfma_f32_16x16x32_bf16(a, bfr[nb], acc2[mbi][nb], 0, 0, 0);
      }
    }

    // ===== S3: q[r] = relu(b3 + sum_c2 relu(H2)*W3)
    float part[4] = {0.f, 0.f, 0.f, 0.f};
    #pragma unroll
    for (int mbi = 0; mbi < 4; ++mbi) {
      int c0 = (w * 4 + mbi) * 16 + g * 4;
      f32x4 w3v = *(const f32x4*)(W3 + c0);
      #pragma unroll
      for (int nb = 0; nb < 4; ++nb) {
        f32x4 v = acc2[mbi][nb];
        part[nb] += fmaxf(v[0], 0.f) * w3v[0] + fmaxf(v[1], 0.f) * w3v[1]
                  + fmaxf(v[2], 0.f) * w3v[2] + fmaxf(v[3], 0.f) * w3v[3];
      }
    }
    #pragma unroll
    for (int nb = 0; nb < 4; ++nb) {
      float p = part[nb];
      p += __shfl_xor(p, 16, 64);
      p += __shfl_xor(p, 32, 64);
      if (g == 0) qpart[w][nb * 16 + ln] = p;
    }
    __syncthreads();  // also protects h1 reuse (S2 reads done) for next sub-tile
    if (t < 64) {
      float q = qpart[0][t] + qpart[1][t] + qpart[2][t] + qpart[3][t]
              + qpart[4][t] + qpart[5][t] + qpart[6][t] + qpart[7][t] + b3[0];
      qout[(size_t)b * 512 + l0 + t] = fmaxf(q, 0.f);
    }
    // next sub-tile's qpart writes are ordered after its S1-end barrier -> no race
  }
}

extern "C" void kernel_launch(void* const* d_in, const int* in_sizes, int n_in,
                              void* d_out, int out_size, void* d_ws, size_t ws_size,
                              hipStream_t stream) {
  (void)in_sizes; (void)n_in; (void)out_size; (void)ws_size;
  const float* instr  = (const float*)d_in[0];
  const float* state  = (const float*)d_in[1];
  const float* hidden = (const float*)d_in[2];
  const float* adesc  = (const float*)d_in[3];
  const float* astd   = (const float*)d_in[4];
  const int*   tids   = (const int*)d_in[5];
  const int*   lens   = (const int*)d_in[6];
  const float* Wd = (const float*)d_in[7];
  const float* bd = (const float*)d_in[8];
  const float* Ws = (const float*)d_in[9];
  const float* bs = (const float*)d_in[10];
  const float* W1 = (const float*)d_in[11];
  const float* b1 = (const float*)d_in[12];
  const float* W2 = (const float*)d_in[13];
  const float* b2 = (const float*)d_in[14];
  const float* W3 = (const float*)d_in[15];
  const float* b3 = (const float*)d_in[16];

  float* qout = (float*)d_out;
  float* embout = qout + 128 * 512;

  char* ws = (char*)d_ws;
  unsigned short* wdf  = (unsigned short*)(ws);             // 196608 B
  unsigned short* wsf  = (unsigned short*)(ws + 196608);    //  32768 B
  unsigned short* w1f  = (unsigned short*)(ws + 229376);    // 131072 B
  unsigned short* w2f  = (unsigned short*)(ws + 360448);    // 524288 B
  float* cc   = (float*)(ws + 884736);                      // 262144 B
  float* qinv = (float*)(ws + 1146880);                     // 512 B
  unsigned short* embB = (unsigned short*)(ws + 1147392);   // 16777216 B

  prep_pack<<<256, 256, 0, stream>>>(Wd, Ws, W1, W2, wdf, wsf, w1f, w2f);
  ctx_cc<<<512, 256, 0, stream>>>(instr, state, hidden, W1, b1, cc);
  qinv_kernel<<<128, 256, 0, stream>>>(cc, W2, b2, W3, b3, qinv);
  emb_kernel<<<dim3(8, 128), 512, 0, stream>>>(adesc, astd, tids, lens, bd, bs,
                                               wdf, wsf, embout, embB);
  mlp_kernel<<<dim3(4, 128), 512, 0, stream>>>(lens, b2, W3, b3, w1f, w2f,
                                               cc, qinv, embB, qout);
}

// Round 7
// 147.861 us; speedup vs baseline: 1.5998x; 1.5998x over previous
//
#include <hip/hip_runtime.h>
#include <hip/hip_bf16.h>
#include <stdint.h>

// FlatCritic: B=128, L=512, D_DESC=768, D_STD=128, D_ACT=128, D_CTX=1152, H=512
// out = [q (B*L f32), emb (B*L*128 f32)]
//
// v7 = v4 (best: 153.7us) + mlp-only fixes:
//  (1) h1 XOR-swizzle, linear [64][512] stride  -> kills 8-way ds_read conflicts
//  (2) wave-staggered ks order in S1/S2         -> de-lockstep L2 weight bursts
// emb / prologue byte-identical to v4.

typedef __attribute__((ext_vector_type(8))) short short8_t;
typedef __attribute__((ext_vector_type(4))) short short4_t;
typedef __attribute__((ext_vector_type(4))) float f32x4;
typedef __attribute__((ext_vector_type(4))) unsigned int u32x4;

__device__ inline unsigned short f2bf(float f) {
  union { float f; unsigned u; } v; v.f = f;
  unsigned r = v.u + 0x7FFFu + ((v.u >> 16) & 1u);
  return (unsigned short)(r >> 16);
}

// A-frag pack (mb-major): dst[((mb*NKS+ks)*64+l)*8+j] = bf16(src[(k0+ks*32+(l>>4)*8+j)*ldc + mb*16+(l&15)])
__device__ inline void pack_frags(const float* __restrict__ src, int ldc, int k0, int NKS,
                                  unsigned short* __restrict__ dst, int total, int tid, int n) {
  for (int fi = tid; fi < total; fi += n) {
    int j = fi & 7, lane = (fi >> 3) & 63, rest = fi >> 9;
    int ks = rest % NKS, mb = rest / NKS;
    int c = mb * 16 + (lane & 15);
    int k = k0 + ks * 32 + ((lane >> 4) << 3) + j;
    dst[fi] = f2bf(src[(size_t)k * ldc + c]);
  }
}

__global__ __launch_bounds__(256) void prep_pack(
    const float* __restrict__ Wd, const float* __restrict__ Ws,
    const float* __restrict__ W1, const float* __restrict__ W2,
    unsigned short* __restrict__ wdf, unsigned short* __restrict__ wsf,
    unsigned short* __restrict__ w1f, unsigned short* __restrict__ w2f) {
  int tid = blockIdx.x * 256 + threadIdx.x, n = gridDim.x * 256;
  pack_frags(Wd, 128, 0,    24, wdf,  98304,  tid, n);   // desc proj  [8mb][24ks]
  pack_frags(Ws, 128, 0,    4,  wsf,  16384,  tid, n);   // std proj   [8mb][4ks]
  pack_frags(W1, 512, 1152, 4,  w1f,  65536,  tid, n);   // W1[1152:]  [32mb][4ks]
  pack_frags(W2, 512, 0,    16, w2f,  262144, tid, n);   // W2         [32mb][16ks]
}

// ---------------- cc[b][h] = b1[h] + ctx(b).W1[:1152,h]  (fp32 exact) ----------------
__global__ __launch_bounds__(256) void ctx_cc(
    const float* __restrict__ instr, const float* __restrict__ state, const float* __restrict__ hidden,
    const float* __restrict__ W1, const float* __restrict__ b1, float* __restrict__ cc) {
  int bid = blockIdx.x;
  int b = bid >> 2, part = bid & 3;
  __shared__ float ctx[1152];
  __shared__ float red[256];
  int t = threadIdx.x;
  for (int i = t; i < 512; i += 256) { ctx[i] = instr[b * 512 + i]; ctx[512 + i] = state[b * 512 + i]; }
  if (t < 128) ctx[1024 + t] = hidden[b * 128 + t];
  __syncthreads();
  int hcol = part * 128 + (t & 127);
  int half = t >> 7;
  float acc = 0.f;
  const float* wp = W1 + (size_t)half * 576 * 512 + hcol;
  #pragma unroll 8
  for (int d = 0; d < 576; ++d) acc = fmaf(ctx[half * 576 + d], wp[(size_t)d * 512], acc);
  red[t] = acc;
  __syncthreads();
  if (t < 128) cc[b * 512 + hcol] = red[t] + red[t + 128] + b1[hcol];
}

// ---------------- q_inv[b]: MLP tail on emb=0 rows (f32 W2) ----------------
__global__ __launch_bounds__(256) void qinv_kernel(
    const float* __restrict__ cc, const float* __restrict__ W2, const float* __restrict__ b2,
    const float* __restrict__ W3, const float* __restrict__ b3, float* __restrict__ qinv) {
  int b = blockIdx.x, t = threadIdx.x;
  __shared__ float h1s[512];
  __shared__ float red[256];
  for (int i = t; i < 512; i += 256) h1s[i] = fmaxf(cc[b * 512 + i], 0.f);
  __syncthreads();
  float a0 = b2[t], a1 = b2[t + 256];
  #pragma unroll 4
  for (int c = 0; c < 512; ++c) {
    float x = h1s[c];
    a0 = fmaf(x, W2[(size_t)c * 512 + t], a0);
    a1 = fmaf(x, W2[(size_t)c * 512 + t + 256], a1);
  }
  red[t] = fmaxf(a0, 0.f) * W3[t] + fmaxf(a1, 0.f) * W3[t + 256];
  __syncthreads();
  for (int s = 128; s > 0; s >>= 1) { if (t < s) red[t] += red[t + s]; __syncthreads(); }
  if (t == 0) qinv[b] = fmaxf(red[0] + b3[0], 0.f);
}

// ---------------- E: emb producer. 32-row tiles, 256 threads, grid (16,128) ----------------
// outputs: embout f32 (final output) + embB bf16 in B-frag-linear layout:
// embB[(((tile*4+ks)*2+nb)*64 + lane)*8 + j] = bf16emb[r=nb*16+(lane&15)][k=ks*32+(lane>>4)*8+j]
__global__ __launch_bounds__(256, 4) void emb_kernel(
    const float* __restrict__ adesc, const float* __restrict__ astd,
    const int* __restrict__ type_ids, const int* __restrict__ lengths,
    const float* __restrict__ bdesc, const float* __restrict__ bstd,
    const unsigned short* __restrict__ wdf, const unsigned short* __restrict__ wsf,
    float* __restrict__ embout, unsigned short* __restrict__ embB) {
  int b = blockIdx.y, lt = blockIdx.x;
  int l0 = lt * 32;
  int t = threadIdx.x;
  int tile = b * 16 + lt;
  int len = lengths[b];
  int nv = len - l0; nv = nv < 0 ? 0 : (nv > 32 ? 32 : nv);
  f32x4 zero4 = {0.f, 0.f, 0.f, 0.f};

  if (nv == 0) {  // fully-invalid tile: emb = 0, embB = 0 (q handled by M)
    float* ep = embout + (size_t)(b * 512 + l0) * 128;
    #pragma unroll
    for (int i = 0; i < 4; ++i) ((f32x4*)ep)[t + i * 256] = zero4;
    u32x4 z4 = {0u, 0u, 0u, 0u};
    u32x4* bp = (u32x4*)(embB + (size_t)tile * 4096);
    bp[t] = z4; bp[t + 256] = z4;
    return;
  }

  __shared__ __align__(16) unsigned short act[2][32 * 136];
  __shared__ int typeL[32];
  int w = t >> 6, l = t & 63, g = l >> 4, ln = l & 15;

  if (t < 32) typeL[t] = type_ids[b * 512 + l0 + t];

  const float* descB = adesc + (size_t)(b * 512 + l0) * 768;
  const float* stdB  = astd  + (size_t)(b * 512 + l0) * 128;

  __syncthreads();  // typeL ready

  // reg-split staging (T14): issue -> [MFMA prev] -> write
  f32x4 stg[4];
  int r0 = t >> 5, c4 = t & 31;

  auto issue = [&](int kc) {
    bool isStd = (kc == 6);
    #pragma unroll
    for (int i = 0; i < 4; ++i) {
      int r = r0 + i * 8;
      bool ok = (r < nv) && ((typeL[r] == 0) != isStd);
      f32x4 v = zero4;
      if (ok) v = isStd ? *(const f32x4*)(stdB + (size_t)r * 128 + c4 * 4)
                        : *(const f32x4*)(descB + (size_t)r * 768 + kc * 128 + c4 * 4);
      stg[i] = v;
    }
  };
  auto writebuf = [&](int kc) {
    unsigned short* buf = act[kc & 1];
    #pragma unroll
    for (int i = 0; i < 4; ++i) {
      short4_t p;
      p[0] = (short)f2bf(stg[i][0]); p[1] = (short)f2bf(stg[i][1]);
      p[2] = (short)f2bf(stg[i][2]); p[3] = (short)f2bf(stg[i][3]);
      *(short4_t*)&buf[(r0 + i * 8) * 136 + c4 * 4] = p;
    }
  };

  issue(0); writebuf(0);

  f32x4 acc[2][2];
  #pragma unroll
  for (int mb = 0; mb < 2; ++mb)
    #pragma unroll
    for (int nb = 0; nb < 2; ++nb) acc[mb][nb] = zero4;

  for (int kc = 0; kc < 7; ++kc) {
    __syncthreads();  // buf[kc&1] writes visible; all prev reads of buf[(kc+1)&1] done
    if (kc < 6) issue(kc + 1);
    const unsigned short* buf = act[kc & 1];
    bool isStd = (kc == 6);
    #pragma unroll
    for (int ks = 0; ks < 4; ++ks) {
      short8_t bfr[2];
      #pragma unroll
      for (int nb = 0; nb < 2; ++nb)
        bfr[nb] = *(const short8_t*)&buf[(nb * 16 + ln) * 136 + ks * 32 + g * 8];
      #pragma unroll
      for (int mb = 0; mb < 2; ++mb) {
        const unsigned short* ap = isStd ? (wsf + ((((w * 2 + mb) * 4 + ks) * 64 + l) << 3))
                                         : (wdf + ((((w * 2 + mb) * 24 + kc * 4 + ks) * 64 + l) << 3));
        short8_t a = *(const short8_t*)ap;
        #pragma unroll
        for (int nb = 0; nb < 2; ++nb)
          acc[mb][nb] = __builtin_amdgcn_mfma_f32_16x16x32_bf16(a, bfr[nb], acc[mb][nb], 0, 0, 0);
      }
    }
    if (kc < 6) writebuf(kc + 1);
  }
  __syncthreads();  // last MFMAs done reading act[0] -> reuse as E

  // epilogue: masked bias + f32 global store + bf16 -> E (act[0], [32][136])
  unsigned short* E = act[0];
  #pragma unroll
  for (int mb = 0; mb < 2; ++mb) {
    int k0 = w * 32 + mb * 16 + g * 4;
    f32x4 bd4 = *(const f32x4*)(bdesc + k0);
    f32x4 bs4 = *(const f32x4*)(bstd + k0);
    #pragma unroll
    for (int nb = 0; nb < 2; ++nb) {
      int r = nb * 16 + ln;
      f32x4 e = acc[mb][nb];
      if (r < nv) { f32x4 bias = (typeL[r] == 0) ? bd4 : bs4; e = e + bias; }
      else e = zero4;
      *(f32x4*)(embout + (size_t)(b * 512 + l0 + r) * 128 + k0) = e;
      short4_t p; p[0] = (short)f2bf(e[0]); p[1] = (short)f2bf(e[1]);
      p[2] = (short)f2bf(e[2]); p[3] = (short)f2bf(e[3]);
      *(short4_t*)&E[r * 136 + k0] = p;
    }
  }
  __syncthreads();

  // export B-frag-linear embB (coalesced 1KB stores)
  unsigned short* bbase = embB + (size_t)tile * 4096;
  #pragma unroll
  for (int ks = 0; ks < 4; ++ks)
    #pragma unroll
    for (int nb = 0; nb < 2; ++nb) {
      short8_t v = *(const short8_t*)&E[(nb * 16 + ln) * 136 + ks * 32 + g * 8];
      *(short8_t*)&bbase[((ks * 2 + nb) * 64 + l) * 8] = v;
    }
}

// ---------------- M: MLP. 64-row tiles, 512 threads, grid (8,128) ----------------
// v7: h1 XOR-swizzled [64][512]; wave-staggered ks order in S1/S2.
__global__ __launch_bounds__(512, 4) void mlp_kernel(
    const int* __restrict__ lengths,
    const float* __restrict__ b2, const float* __restrict__ W3, const float* __restrict__ b3,
    const unsigned short* __restrict__ w1f, const unsigned short* __restrict__ w2f,
    const float* __restrict__ cc, const float* __restrict__ qinv,
    const unsigned short* __restrict__ embB, float* __restrict__ qout) {
  int b = blockIdx.y, lt = blockIdx.x;
  int l0 = lt * 64;
  int t = threadIdx.x;
  int len = lengths[b];
  int nv = len - l0; nv = nv < 0 ? 0 : (nv > 64 ? 64 : nv);

  if (nv == 0) {
    if (t < 64) qout[(size_t)b * 512 + l0 + t] = qinv[b];
    return;
  }

  __shared__ __align__(16) unsigned short h1[64 * 512];  // XOR-swizzled, linear stride
  __shared__ float qpart[8][64];
  int w = t >> 6, l = t & 63, g = l >> 4, ln = l & 15;

  // ===== S1: H1T[c1][r] = cc[b][c1] + sum_k W1e[k][c1]*emb[r][k]; B-frags from embB
  f32x4 acc1[4][4];
  #pragma unroll
  for (int mbi = 0; mbi < 4; ++mbi) {
    f32x4 ccv = *(const f32x4*)(cc + (size_t)b * 512 + (w * 4 + mbi) * 16 + g * 4);
    #pragma unroll
    for (int nb = 0; nb < 4; ++nb) acc1[mbi][nb] = ccv;
  }
  const unsigned short* ebase = embB + (size_t)(b * 16 + lt * 2) * 4096;  // two 32-row half-tiles
  #pragma unroll
  for (int kk = 0; kk < 4; ++kk) {
    int ks = (kk + w) & 3;  // wave-staggered K order (accumulation order only)
    short8_t bfr[4];
    #pragma unroll
    for (int nb = 0; nb < 4; ++nb)
      bfr[nb] = *(const short8_t*)&ebase[(nb >> 1) * 4096 + ((ks * 2 + (nb & 1)) * 64 + l) * 8];
    #pragma unroll
    for (int mbi = 0; mbi < 4; ++mbi) {
      short8_t a = *(const short8_t*)(w1f + ((((w * 4 + mbi) * 4 + ks) * 64 + l) << 3));
      #pragma unroll
      for (int nb = 0; nb < 4; ++nb)
        acc1[mbi][nb] = __builtin_amdgcn_mfma_f32_16x16x32_bf16(a, bfr[nb], acc1[mbi][nb], 0, 0, 0);
    }
  }
  // relu + pack H1 bf16 -> LDS (write with same XOR swizzle as read)
  #pragma unroll
  for (int mbi = 0; mbi < 4; ++mbi) {
    int c0 = (w * 4 + mbi) * 16 + g * 4;
    #pragma unroll
    for (int nb = 0; nb < 4; ++nb) {
      int r = nb * 16 + ln;
      f32x4 v = acc1[mbi][nb];
      short4_t p;
      p[0] = (short)f2bf(fmaxf(v[0], 0.f)); p[1] = (short)f2bf(fmaxf(v[1], 0.f));
      p[2] = (short)f2bf(fmaxf(v[2], 0.f)); p[3] = (short)f2bf(fmaxf(v[3], 0.f));
      *(short4_t*)&h1[r * 512 + (c0 ^ ((r & 7) << 3))] = p;
    }
  }
  __syncthreads();

  // ===== S2: H2T[c2][r] = b2[c2] + sum_c1 W2[c1][c2]*H1[r][c1]
  f32x4 acc2[4][4];
  #pragma unroll
  for (int mbi = 0; mbi < 4; ++mbi) {
    f32x4 b2v = *(const f32x4*)(b2 + (w * 4 + mbi) * 16 + g * 4);
    #pragma unroll
    for (int nb = 0; nb < 4; ++nb) acc2[mbi][nb] = b2v;
  }
  #pragma unroll
  for (int kk = 0; kk < 16; ++kk) {
    int ks = (kk + 2 * w) & 15;  // wave-staggered K order
    short8_t bfr[4];
    #pragma unroll
    for (int nb = 0; nb < 4; ++nb) {
      int row = nb * 16 + ln;
      bfr[nb] = *(const short8_t*)&h1[row * 512 + ((ks * 32 + g * 8) ^ ((row & 7) << 3))];
    }
    #pragma unroll
    for (int mbi = 0; mbi < 4; ++mbi) {
      short8_t a = *(const short8_t*)(w2f + ((((w * 4 + mbi) * 16 + ks) * 64 + l) << 3));
      #pragma unroll
      for (int nb = 0; nb < 4; ++nb)
        acc2[mbi][nb] = __builtin_amdgcn_mfma_f32_16x16x32_bf16(a, bfr[nb], acc2[mbi][nb], 0, 0, 0);
    }
  }

  // ===== S3: q[r] = relu(b3 + sum_c2 relu(H2)*W3)
  float part[4] = {0.f, 0.f, 0.f, 0.f};
  #pragma unroll
  for (int mbi = 0; mbi < 4; ++mbi) {
    int c0 = (w * 4 + mbi) * 16 + g * 4;
    f32x4 w3v = *(const f32x4*)(W3 + c0);
    #pragma unroll
    for (int nb = 0; nb < 4; ++nb) {
      f32x4 v = acc2[mbi][nb];
      part[nb] += fmaxf(v[0], 0.f) * w3v[0] + fmaxf(v[1], 0.f) * w3v[1]
                + fmaxf(v[2], 0.f) * w3v[2] + fmaxf(v[3], 0.f) * w3v[3];
    }
  }
  #pragma unroll
  for (int nb = 0; nb < 4; ++nb) {
    float p = part[nb];
    p += __shfl_xor(p, 16, 64);
    p += __shfl_xor(p, 32, 64);
    if (g == 0) qpart[w][nb * 16 + ln] = p;
  }
  __syncthreads();
  if (t < 64) {
    float q = qpart[0][t] + qpart[1][t] + qpart[2][t] + qpart[3][t]
            + qpart[4][t] + qpart[5][t] + qpart[6][t] + qpart[7][t] + b3[0];
    qout[(size_t)b * 512 + l0 + t] = fmaxf(q, 0.f);
  }
}

extern "C" void kernel_launch(void* const* d_in, const int* in_sizes, int n_in,
                              void* d_out, int out_size, void* d_ws, size_t ws_size,
                              hipStream_t stream) {
  (void)in_sizes; (void)n_in; (void)out_size; (void)ws_size;
  const float* instr  = (const float*)d_in[0];
  const float* state  = (const float*)d_in[1];
  const float* hidden = (const float*)d_in[2];
  const float* adesc  = (const float*)d_in[3];
  const float* astd   = (const float*)d_in[4];
  const int*   tids   = (const int*)d_in[5];
  const int*   lens   = (const int*)d_in[6];
  const float* Wd = (const float*)d_in[7];
  const float* bd = (const float*)d_in[8];
  const float* Ws = (const float*)d_in[9];
  const float* bs = (const float*)d_in[10];
  const float* W1 = (const float*)d_in[11];
  const float* b1 = (const float*)d_in[12];
  const float* W2 = (const float*)d_in[13];
  const float* b2 = (const float*)d_in[14];
  const float* W3 = (const float*)d_in[15];
  const float* b3 = (const float*)d_in[16];

  float* qout = (float*)d_out;
  float* embout = qout + 128 * 512;

  char* ws = (char*)d_ws;
  unsigned short* wdf  = (unsigned short*)(ws);             // 196608 B
  unsigned short* wsf  = (unsigned short*)(ws + 196608);    //  32768 B
  unsigned short* w1f  = (unsigned short*)(ws + 229376);    // 131072 B
  unsigned short* w2f  = (unsigned short*)(ws + 360448);    // 524288 B
  float* cc   = (float*)(ws + 884736);                      // 262144 B
  float* qinv = (float*)(ws + 1146880);                     // 512 B
  unsigned short* embB = (unsigned short*)(ws + 1147392);   // 16777216 B

  prep_pack<<<256, 256, 0, stream>>>(Wd, Ws, W1, W2, wdf, wsf, w1f, w2f);
  ctx_cc<<<512, 256, 0, stream>>>(instr, state, hidden, W1, b1, cc);
  qinv_kernel<<<128, 256, 0, stream>>>(cc, W2, b2, W3, b3, qinv);
  emb_kernel<<<dim3(16, 128), 256, 0, stream>>>(adesc, astd, tids, lens, bd, bs,
                                                wdf, wsf, embout, embB);
  mlp_kernel<<<dim3(8, 128), 512, 0, stream>>>(lens, b2, W3, b3, w1f, w2f,
                                               cc, qinv, embB, qout);
}

// Round 8
// 144.312 us; speedup vs baseline: 1.6391x; 1.0246x over previous
//
#include <hip/hip_runtime.h>
#include <hip/hip_bf16.h>
#include <stdint.h>

// FlatCritic: B=128, L=512, D_DESC=768, D_STD=128, D_ACT=128, D_CTX=1152, H=512
// out = [q (B*L f32), emb (B*L*128 f32)]
//
// v8 = v7 (emb/prologue unchanged) + fat mlp:
//  - 128-row blocks (grid 4x128), h1[128][512] bf16 in LDS (128KB, 1 block/CU)
//  - each w2f fragment reused across 8 row-fragments (2x arithmetic intensity,
//    w2f traffic 295->164 MB)
//  - manual 1-deep ping-pong prefetch of w2f A-frags (static kk&1 idx),
//    __launch_bounds__(512,2) for VGPR headroom, setprio(1) around MFMA burst

typedef __attribute__((ext_vector_type(8))) short short8_t;
typedef __attribute__((ext_vector_type(4))) short short4_t;
typedef __attribute__((ext_vector_type(4))) float f32x4;
typedef __attribute__((ext_vector_type(4))) unsigned int u32x4;

__device__ inline unsigned short f2bf(float f) {
  union { float f; unsigned u; } v; v.f = f;
  unsigned r = v.u + 0x7FFFu + ((v.u >> 16) & 1u);
  return (unsigned short)(r >> 16);
}

// A-frag pack (mb-major): dst[((mb*NKS+ks)*64+l)*8+j] = bf16(src[(k0+ks*32+(l>>4)*8+j)*ldc + mb*16+(l&15)])
__device__ inline void pack_frags(const float* __restrict__ src, int ldc, int k0, int NKS,
                                  unsigned short* __restrict__ dst, int total, int tid, int n) {
  for (int fi = tid; fi < total; fi += n) {
    int j = fi & 7, lane = (fi >> 3) & 63, rest = fi >> 9;
    int ks = rest % NKS, mb = rest / NKS;
    int c = mb * 16 + (lane & 15);
    int k = k0 + ks * 32 + ((lane >> 4) << 3) + j;
    dst[fi] = f2bf(src[(size_t)k * ldc + c]);
  }
}

__global__ __launch_bounds__(256) void prep_pack(
    const float* __restrict__ Wd, const float* __restrict__ Ws,
    const float* __restrict__ W1, const float* __restrict__ W2,
    unsigned short* __restrict__ wdf, unsigned short* __restrict__ wsf,
    unsigned short* __restrict__ w1f, unsigned short* __restrict__ w2f) {
  int tid = blockIdx.x * 256 + threadIdx.x, n = gridDim.x * 256;
  pack_frags(Wd, 128, 0,    24, wdf,  98304,  tid, n);   // desc proj  [8mb][24ks]
  pack_frags(Ws, 128, 0,    4,  wsf,  16384,  tid, n);   // std proj   [8mb][4ks]
  pack_frags(W1, 512, 1152, 4,  w1f,  65536,  tid, n);   // W1[1152:]  [32mb][4ks]
  pack_frags(W2, 512, 0,    16, w2f,  262144, tid, n);   // W2         [32mb][16ks]
}

// ---------------- cc[b][h] = b1[h] + ctx(b).W1[:1152,h]  (fp32 exact) ----------------
__global__ __launch_bounds__(256) void ctx_cc(
    const float* __restrict__ instr, const float* __restrict__ state, const float* __restrict__ hidden,
    const float* __restrict__ W1, const float* __restrict__ b1, float* __restrict__ cc) {
  int bid = blockIdx.x;
  int b = bid >> 2, part = bid & 3;
  __shared__ float ctx[1152];
  __shared__ float red[256];
  int t = threadIdx.x;
  for (int i = t; i < 512; i += 256) { ctx[i] = instr[b * 512 + i]; ctx[512 + i] = state[b * 512 + i]; }
  if (t < 128) ctx[1024 + t] = hidden[b * 128 + t];
  __syncthreads();
  int hcol = part * 128 + (t & 127);
  int half = t >> 7;
  float acc = 0.f;
  const float* wp = W1 + (size_t)half * 576 * 512 + hcol;
  #pragma unroll 8
  for (int d = 0; d < 576; ++d) acc = fmaf(ctx[half * 576 + d], wp[(size_t)d * 512], acc);
  red[t] = acc;
  __syncthreads();
  if (t < 128) cc[b * 512 + hcol] = red[t] + red[t + 128] + b1[hcol];
}

// ---------------- q_inv[b]: MLP tail on emb=0 rows (f32 W2) ----------------
__global__ __launch_bounds__(256) void qinv_kernel(
    const float* __restrict__ cc, const float* __restrict__ W2, const float* __restrict__ b2,
    const float* __restrict__ W3, const float* __restrict__ b3, float* __restrict__ qinv) {
  int b = blockIdx.x, t = threadIdx.x;
  __shared__ float h1s[512];
  __shared__ float red[256];
  for (int i = t; i < 512; i += 256) h1s[i] = fmaxf(cc[b * 512 + i], 0.f);
  __syncthreads();
  float a0 = b2[t], a1 = b2[t + 256];
  #pragma unroll 4
  for (int c = 0; c < 512; ++c) {
    float x = h1s[c];
    a0 = fmaf(x, W2[(size_t)c * 512 + t], a0);
    a1 = fmaf(x, W2[(size_t)c * 512 + t + 256], a1);
  }
  red[t] = fmaxf(a0, 0.f) * W3[t] + fmaxf(a1, 0.f) * W3[t + 256];
  __syncthreads();
  for (int s = 128; s > 0; s >>= 1) { if (t < s) red[t] += red[t + s]; __syncthreads(); }
  if (t == 0) qinv[b] = fmaxf(red[0] + b3[0], 0.f);
}

// ---------------- E: emb producer. 32-row tiles, 256 threads, grid (16,128) ----------------
// outputs: embout f32 (final output) + embB bf16 in B-frag-linear layout:
// embB[(((tile*4+ks)*2+nb)*64 + lane)*8 + j] = bf16emb[r=nb*16+(lane&15)][k=ks*32+(lane>>4)*8+j]
__global__ __launch_bounds__(256, 4) void emb_kernel(
    const float* __restrict__ adesc, const float* __restrict__ astd,
    const int* __restrict__ type_ids, const int* __restrict__ lengths,
    const float* __restrict__ bdesc, const float* __restrict__ bstd,
    const unsigned short* __restrict__ wdf, const unsigned short* __restrict__ wsf,
    float* __restrict__ embout, unsigned short* __restrict__ embB) {
  int b = blockIdx.y, lt = blockIdx.x;
  int l0 = lt * 32;
  int t = threadIdx.x;
  int tile = b * 16 + lt;
  int len = lengths[b];
  int nv = len - l0; nv = nv < 0 ? 0 : (nv > 32 ? 32 : nv);
  f32x4 zero4 = {0.f, 0.f, 0.f, 0.f};

  if (nv == 0) {  // fully-invalid tile: emb = 0, embB = 0 (q handled by M)
    float* ep = embout + (size_t)(b * 512 + l0) * 128;
    #pragma unroll
    for (int i = 0; i < 4; ++i) ((f32x4*)ep)[t + i * 256] = zero4;
    u32x4 z4 = {0u, 0u, 0u, 0u};
    u32x4* bp = (u32x4*)(embB + (size_t)tile * 4096);
    bp[t] = z4; bp[t + 256] = z4;
    return;
  }

  __shared__ __align__(16) unsigned short act[2][32 * 136];
  __shared__ int typeL[32];
  int w = t >> 6, l = t & 63, g = l >> 4, ln = l & 15;

  if (t < 32) typeL[t] = type_ids[b * 512 + l0 + t];

  const float* descB = adesc + (size_t)(b * 512 + l0) * 768;
  const float* stdB  = astd  + (size_t)(b * 512 + l0) * 128;

  __syncthreads();  // typeL ready

  // reg-split staging (T14): issue -> [MFMA prev] -> write
  f32x4 stg[4];
  int r0 = t >> 5, c4 = t & 31;

  auto issue = [&](int kc) {
    bool isStd = (kc == 6);
    #pragma unroll
    for (int i = 0; i < 4; ++i) {
      int r = r0 + i * 8;
      bool ok = (r < nv) && ((typeL[r] == 0) != isStd);
      f32x4 v = zero4;
      if (ok) v = isStd ? *(const f32x4*)(stdB + (size_t)r * 128 + c4 * 4)
                        : *(const f32x4*)(descB + (size_t)r * 768 + kc * 128 + c4 * 4);
      stg[i] = v;
    }
  };
  auto writebuf = [&](int kc) {
    unsigned short* buf = act[kc & 1];
    #pragma unroll
    for (int i = 0; i < 4; ++i) {
      short4_t p;
      p[0] = (short)f2bf(stg[i][0]); p[1] = (short)f2bf(stg[i][1]);
      p[2] = (short)f2bf(stg[i][2]); p[3] = (short)f2bf(stg[i][3]);
      *(short4_t*)&buf[(r0 + i * 8) * 136 + c4 * 4] = p;
    }
  };

  issue(0); writebuf(0);

  f32x4 acc[2][2];
  #pragma unroll
  for (int mb = 0; mb < 2; ++mb)
    #pragma unroll
    for (int nb = 0; nb < 2; ++nb) acc[mb][nb] = zero4;

  for (int kc = 0; kc < 7; ++kc) {
    __syncthreads();  // buf[kc&1] writes visible; all prev reads of buf[(kc+1)&1] done
    if (kc < 6) issue(kc + 1);
    const unsigned short* buf = act[kc & 1];
    bool isStd = (kc == 6);
    #pragma unroll
    for (int ks = 0; ks < 4; ++ks) {
      short8_t bfr[2];
      #pragma unroll
      for (int nb = 0; nb < 2; ++nb)
        bfr[nb] = *(const short8_t*)&buf[(nb * 16 + ln) * 136 + ks * 32 + g * 8];
      #pragma unroll
      for (int mb = 0; mb < 2; ++mb) {
        const unsigned short* ap = isStd ? (wsf + ((((w * 2 + mb) * 4 + ks) * 64 + l) << 3))
                                         : (wdf + ((((w * 2 + mb) * 24 + kc * 4 + ks) * 64 + l) << 3));
        short8_t a = *(const short8_t*)ap;
        #pragma unroll
        for (int nb = 0; nb < 2; ++nb)
          acc[mb][nb] = __builtin_amdgcn_mfma_f32_16x16x32_bf16(a, bfr[nb], acc[mb][nb], 0, 0, 0);
      }
    }
    if (kc < 6) writebuf(kc + 1);
  }
  __syncthreads();  // last MFMAs done reading act[0] -> reuse as E

  // epilogue: masked bias + f32 global store + bf16 -> E (act[0], [32][136])
  unsigned short* E = act[0];
  #pragma unroll
  for (int mb = 0; mb < 2; ++mb) {
    int k0 = w * 32 + mb * 16 + g * 4;
    f32x4 bd4 = *(const f32x4*)(bdesc + k0);
    f32x4 bs4 = *(const f32x4*)(bstd + k0);
    #pragma unroll
    for (int nb = 0; nb < 2; ++nb) {
      int r = nb * 16 + ln;
      f32x4 e = acc[mb][nb];
      if (r < nv) { f32x4 bias = (typeL[r] == 0) ? bd4 : bs4; e = e + bias; }
      else e = zero4;
      *(f32x4*)(embout + (size_t)(b * 512 + l0 + r) * 128 + k0) = e;
      short4_t p; p[0] = (short)f2bf(e[0]); p[1] = (short)f2bf(e[1]);
      p[2] = (short)f2bf(e[2]); p[3] = (short)f2bf(e[3]);
      *(short4_t*)&E[r * 136 + k0] = p;
    }
  }
  __syncthreads();

  // export B-frag-linear embB (coalesced 1KB stores)
  unsigned short* bbase = embB + (size_t)tile * 4096;
  #pragma unroll
  for (int ks = 0; ks < 4; ++ks)
    #pragma unroll
    for (int nb = 0; nb < 2; ++nb) {
      short8_t v = *(const short8_t*)&E[(nb * 16 + ln) * 136 + ks * 32 + g * 8];
      *(short8_t*)&bbase[((ks * 2 + nb) * 64 + l) * 8] = v;
    }
}

// ---------------- M: MLP. 128-row blocks, 512 thr, grid (4,128) ----------------
// h1[128][512] bf16 XOR-swizzled (128KB, 1 block/CU); w2f frags shared across
// 8 row-frags; 1-deep ping-pong prefetch; setprio around MFMA bursts.
__global__ __launch_bounds__(512, 2) void mlp_kernel(
    const int* __restrict__ lengths,
    const float* __restrict__ b2, const float* __restrict__ W3, const float* __restrict__ b3,
    const unsigned short* __restrict__ w1f, const unsigned short* __restrict__ w2f,
    const float* __restrict__ cc, const float* __restrict__ qinv,
    const unsigned short* __restrict__ embB, float* __restrict__ qout) {
  int b = blockIdx.y, lt = blockIdx.x;
  int l0 = lt * 128;
  int t = threadIdx.x;
  int len = lengths[b];
  int nv = len - l0; nv = nv < 0 ? 0 : (nv > 128 ? 128 : nv);

  if (nv == 0) {
    if (t < 128) qout[(size_t)b * 512 + l0 + t] = qinv[b];
    return;
  }

  __shared__ __align__(16) unsigned short h1[128 * 512];  // XOR-swizzled
  __shared__ float qpart[8][128];
  int w = t >> 6, l = t & 63, g = l >> 4, ln = l & 15;

  // ===== S1: H1T[c1][r] = cc[b][c1] + sum_k W1e[k][c1]*emb[r][k]; rows 0..127
  f32x4 acc[4][8];
  #pragma unroll
  for (int mbi = 0; mbi < 4; ++mbi) {
    f32x4 ccv = *(const f32x4*)(cc + (size_t)b * 512 + (w * 4 + mbi) * 16 + g * 4);
    #pragma unroll
    for (int nb = 0; nb < 8; ++nb) acc[mbi][nb] = ccv;
  }
  const unsigned short* ebase = embB + (size_t)(b * 16 + lt * 4) * 4096;  // 4 half-tiles
  #pragma unroll
  for (int kk = 0; kk < 4; ++kk) {
    int ks = (kk + w) & 3;  // wave-staggered K order
    short8_t bfr[8];
    #pragma unroll
    for (int nb = 0; nb < 8; ++nb)
      bfr[nb] = *(const short8_t*)&ebase[(nb >> 1) * 4096 + ((ks * 2 + (nb & 1)) * 64 + l) * 8];
    short8_t a[4];
    #pragma unroll
    for (int mbi = 0; mbi < 4; ++mbi)
      a[mbi] = *(const short8_t*)(w1f + ((((w * 4 + mbi) * 4 + ks) * 64 + l) << 3));
    __builtin_amdgcn_s_setprio(1);
    #pragma unroll
    for (int mbi = 0; mbi < 4; ++mbi)
      #pragma unroll
      for (int nb = 0; nb < 8; ++nb)
        acc[mbi][nb] = __builtin_amdgcn_mfma_f32_16x16x32_bf16(a[mbi], bfr[nb], acc[mbi][nb], 0, 0, 0);
    __builtin_amdgcn_s_setprio(0);
  }
  // relu + pack H1 bf16 -> LDS (same XOR swizzle on write and read)
  #pragma unroll
  for (int mbi = 0; mbi < 4; ++mbi) {
    int c0 = (w * 4 + mbi) * 16 + g * 4;
    #pragma unroll
    for (int nb = 0; nb < 8; ++nb) {
      int r = nb * 16 + ln;
      f32x4 v = acc[mbi][nb];
      short4_t p;
      p[0] = (short)f2bf(fmaxf(v[0], 0.f)); p[1] = (short)f2bf(fmaxf(v[1], 0.f));
      p[2] = (short)f2bf(fmaxf(v[2], 0.f)); p[3] = (short)f2bf(fmaxf(v[3], 0.f));
      *(short4_t*)&h1[r * 512 + (c0 ^ ((r & 7) << 3))] = p;
    }
  }
  __syncthreads();

  // ===== S2: H2T[c2][r] = b2[c2] + sum_c1 W2[c1][c2]*H1[r][c1]
  #pragma unroll
  for (int mbi = 0; mbi < 4; ++mbi) {
    f32x4 b2v = *(const f32x4*)(b2 + (w * 4 + mbi) * 16 + g * 4);
    #pragma unroll
    for (int nb = 0; nb < 8; ++nb) acc[mbi][nb] = b2v;
  }
  int ks0 = (2 * w) & 15;
  short8_t aP[2][4];
  #pragma unroll
  for (int mbi = 0; mbi < 4; ++mbi)
    aP[0][mbi] = *(const short8_t*)(w2f + ((((w * 4 + mbi) * 16 + ks0) * 64 + l) << 3));
  #pragma unroll
  for (int kk = 0; kk < 16; ++kk) {
    int ksn = (kk + 1 + 2 * w) & 15;
    if (kk < 15) {  // prefetch next iteration's w2f frags (ping-pong, static idx)
      #pragma unroll
      for (int mbi = 0; mbi < 4; ++mbi)
        aP[(kk + 1) & 1][mbi] =
            *(const short8_t*)(w2f + ((((w * 4 + mbi) * 16 + ksn) * 64 + l) << 3));
    }
    int ks = (kk + 2 * w) & 15;
    short8_t bfr[8];
    #pragma unroll
    for (int nb = 0; nb < 8; ++nb) {
      int row = nb * 16 + ln;
      bfr[nb] = *(const short8_t*)&h1[row * 512 + ((ks * 32 + g * 8) ^ ((row & 7) << 3))];
    }
    __builtin_amdgcn_s_setprio(1);
    #pragma unroll
    for (int mbi = 0; mbi < 4; ++mbi)
      #pragma unroll
      for (int nb = 0; nb < 8; ++nb)
        acc[mbi][nb] = __builtin_amdgcn_mfma_f32_16x16x32_bf16(aP[kk & 1][mbi], bfr[nb], acc[mbi][nb], 0, 0, 0);
    __builtin_amdgcn_s_setprio(0);
  }

  // ===== S3: q[r] = relu(b3 + sum_c2 relu(H2)*W3)
  float part[8] = {0.f, 0.f, 0.f, 0.f, 0.f, 0.f, 0.f, 0.f};
  #pragma unroll
  for (int mbi = 0; mbi < 4; ++mbi) {
    int c0 = (w * 4 + mbi) * 16 + g * 4;
    f32x4 w3v = *(const f32x4*)(W3 + c0);
    #pragma unroll
    for (int nb = 0; nb < 8; ++nb) {
      f32x4 v = acc[mbi][nb];
      part[nb] += fmaxf(v[0], 0.f) * w3v[0] + fmaxf(v[1], 0.f) * w3v[1]
                + fmaxf(v[2], 0.f) * w3v[2] + fmaxf(v[3], 0.f) * w3v[3];
    }
  }
  #pragma unroll
  for (int nb = 0; nb < 8; ++nb) {
    float p = part[nb];
    p += __shfl_xor(p, 16, 64);
    p += __shfl_xor(p, 32, 64);
    if (g == 0) qpart[w][nb * 16 + ln] = p;
  }
  __syncthreads();
  if (t < 128) {
    float q = qpart[0][t] + qpart[1][t] + qpart[2][t] + qpart[3][t]
            + qpart[4][t] + qpart[5][t] + qpart[6][t] + qpart[7][t] + b3[0];
    qout[(size_t)b * 512 + l0 + t] = fmaxf(q, 0.f);
  }
}

extern "C" void kernel_launch(void* const* d_in, const int* in_sizes, int n_in,
                              void* d_out, int out_size, void* d_ws, size_t ws_size,
                              hipStream_t stream) {
  (void)in_sizes; (void)n_in; (void)out_size; (void)ws_size;
  const float* instr  = (const float*)d_in[0];
  const float* state  = (const float*)d_in[1];
  const float* hidden = (const float*)d_in[2];
  const float* adesc  = (const float*)d_in[3];
  const float* astd   = (const float*)d_in[4];
  const int*   tids   = (const int*)d_in[5];
  const int*   lens   = (const int*)d_in[6];
  const float* Wd = (const float*)d_in[7];
  const float* bd = (const float*)d_in[8];
  const float* Ws = (const float*)d_in[9];
  const float* bs = (const float*)d_in[10];
  const float* W1 = (const float*)d_in[11];
  const float* b1 = (const float*)d_in[12];
  const float* W2 = (const float*)d_in[13];
  const float* b2 = (const float*)d_in[14];
  const float* W3 = (const float*)d_in[15];
  const float* b3 = (const float*)d_in[16];

  float* qout = (float*)d_out;
  float* embout = qout + 128 * 512;

  char* ws = (char*)d_ws;
  unsigned short* wdf  = (unsigned short*)(ws);             // 196608 B
  unsigned short* wsf  = (unsigned short*)(ws + 196608);    //  32768 B
  unsigned short* w1f  = (unsigned short*)(ws + 229376);    // 131072 B
  unsigned short* w2f  = (unsigned short*)(ws + 360448);    // 524288 B
  float* cc   = (float*)(ws + 884736);                      // 262144 B
  float* qinv = (float*)(ws + 1146880);                     // 512 B
  unsigned short* embB = (unsigned short*)(ws + 1147392);   // 16777216 B

  prep_pack<<<256, 256, 0, stream>>>(Wd, Ws, W1, W2, wdf, wsf, w1f, w2f);
  ctx_cc<<<512, 256, 0, stream>>>(instr, state, hidden, W1, b1, cc);
  qinv_kernel<<<128, 256, 0, stream>>>(cc, W2, b2, W3, b3, qinv);
  emb_kernel<<<dim3(16, 128), 256, 0, stream>>>(adesc, astd, tids, lens, bd, bs,
                                                wdf, wsf, embout, embB);
  mlp_kernel<<<dim3(4, 128), 512, 0, stream>>>(lens, b2, W3, b3, w1f, w2f,
                                               cc, qinv, embB, qout);
}